// Round 5
// baseline (428.000 us; speedup 1.0000x reference)
//
#include <hip/hip_runtime.h>

// GetCostVolume: out shape (B=4, 2C=64, D=48, H=64, W=128) fp32
//   c <  32: out[b,c,d,h,w] = (w>=d) ? x[b,c,h,w]      : 0
//   c >= 32: out[b,c,d,h,w] = (w>=d) ? y[b,c-32,h,w-d] : 0
//
// Round 6: fill-mimic phased-linear front (decisive A/B vs R0).
//   Evidence so far (kernel residual = dur_us - ~258us constant re-poison fill):
//     R0  2048 WGs, d-strided scatter        ~130us (3.1 TB/s write)
//     R4  98304 WGs, 1 store each            ~172us (WG-dispatch-bound)
//     R5  3072 WGs, 128KB contiguous/block   ~144us
//   The fill achieves 6.25 TB/s with: few WGs + grid-stride so ALL threads
//   write one contiguous ~8MB window that marches monotonically. No prior
//   version reproduced that. This one does, exactly:
//     thread tid writes flat float4 indices  i = k*524288 + tid, k=0..47.
//   Same WG count and per-thread store count as R0 -> clean A/B on the
//   address pattern alone.
//   Per iteration the wave decomposes i: w4=i&31, h=(i>>5)&63, slice=i>>11
//   (wave-uniform) -> d=slice%48, cc, b. Branch cc<32 is wave-uniform.
//   y-half: aligned float4 load (L2-hit; inputs 8MB, 48x reuse) + chained
//   __shfl_up window with wave-uniform s=d>>2, r=d&3; intra-float4 rotation
//   via uniform switch on r. Clamped-shuffle lanes (w4<s => w<d) coincide
//   with masked lanes — same verified algebra as R0/R5.
//   If this lands ~65-80us: front tightness was the mechanism.
//   If it stays ~130us: pure-write ceiling ~3.1 TB/s -> R0 was roofline.

__global__ __launch_bounds__(256) void cost_volume_kernel(
    const float* __restrict__ x, const float* __restrict__ y,
    float4* __restrict__ out)
{
    const int tid = blockIdx.x * 256 + threadIdx.x;   // 524,288 threads

#pragma unroll 4
    for (int k = 0; k < 48; ++k) {
        const int i  = k * 524288 + tid;  // flat float4 index (phased window)
        const int w4 = i & 31;
        const int w0 = w4 << 2;
        const int h  = (i >> 5) & 63;
        const int sl = i >> 11;           // (b*64+cc)*48 + d  (wave-uniform)
        const int d  = sl % 48;
        const int q  = sl / 48;
        const int cc = q & 63;
        const int b  = q >> 6;

        float4 v;
        if (cc < 32) {
            v = *(const float4*)(x + (((b * 32 + cc) * 64 + h) << 7) + w0);
        } else {
            const float4 yv =
                *(const float4*)(y + (((b * 32 + (cc - 32)) * 64 + h) << 7) + w0);
            const int s = d >> 2;         // whole-float4 shift (wave-uniform)
            const int r = d & 3;          // intra-float4 shift (wave-uniform)
            float4 c2, p2;
            c2.x = __shfl_up(yv.x, s, 32);
            c2.y = __shfl_up(yv.y, s, 32);
            c2.z = __shfl_up(yv.z, s, 32);
            c2.w = __shfl_up(yv.w, s, 32);
            p2.x = __shfl_up(yv.x, s + 1, 32);
            p2.y = __shfl_up(yv.y, s + 1, 32);
            p2.z = __shfl_up(yv.z, s + 1, 32);
            p2.w = __shfl_up(yv.w, s + 1, 32);
            // element j: (j>=r) ? c2[j-r] : p2[4+j-r]   (r wave-uniform)
            switch (r) {
                case 0:  v = c2; break;
                case 1:  v = make_float4(p2.w, c2.x, c2.y, c2.z); break;
                case 2:  v = make_float4(p2.z, p2.w, c2.x, c2.y); break;
                default: v = make_float4(p2.y, p2.z, p2.w, c2.x); break;
            }
        }
        // mask w >= d
        v.x = (w0 + 0 >= d) ? v.x : 0.0f;
        v.y = (w0 + 1 >= d) ? v.y : 0.0f;
        v.z = (w0 + 2 >= d) ? v.z : 0.0f;
        v.w = (w0 + 3 >= d) ? v.w : 0.0f;

        out[i] = v;
    }
}

extern "C" void kernel_launch(void* const* d_in, const int* in_sizes, int n_in,
                              void* d_out, int out_size, void* d_ws, size_t ws_size,
                              hipStream_t stream) {
    const float* x = (const float*)d_in[0];
    const float* y = (const float*)d_in[1];
    float4* out = (float4*)d_out;

    const int block = 256;
    const int grid  = 2048;   // 524,288 threads; 48 phased-linear stores each
    cost_volume_kernel<<<grid, block, 0, stream>>>(x, y, out);
}